// Round 2
// baseline (327.947 us; speedup 1.0000x reference)
//
#include <hip/hip_runtime.h>
#include <hip/hip_cooperative_groups.h>

// x (4096, 2, 1024) fp32.  P_i = x[i,0,:], A_j = x[i,1,:]
// out[0] = 1.0 exactly; out[1] = prec1 = 100*mean(argmax_j sim[i,j] == i)
// argmax_j sim[i,j] == argmax_j dot(P_i,A_j)*inv_norm(A_j).
// R14: single cooperative kernel. Evidence: R12/R13 top-5 are ALL the 58us
// GEMM -> prep was never ~65us; the ~73us/iter gap is non-kernel time
// (graph node replay + reset dispatches). Fuse norms+conv+GEMM+finalize into
// one dispatch with grid.sync(), keeping the GEMM core byte-identical.
// Frag-order map (R4/R9/R11-verified): block fb region = 64KB at fb*65536;
// byte = kh*1024 + lane*16 -> (row = fb*32 + (lane&31), k = kh*16+(lane>>5)*8..+8).

namespace cg = cooperative_groups;

#define NROWS 4096
#define DDIM  1024
#define XSTR  2048

typedef unsigned int u32;
typedef unsigned long long u64;
typedef __attribute__((ext_vector_type(8))) short bf16x8;
typedef __attribute__((ext_vector_type(8))) unsigned short u16x8;
typedef __attribute__((ext_vector_type(16))) float f32x16;

__device__ __forceinline__ unsigned int fkey(float f) {
    unsigned int u = __float_as_uint(f);
    return (u & 0x80000000u) ? ~u : (u | 0x80000000u);
}

__device__ __forceinline__ u64 shfl_xor_u64(u64 v, int m) {
    unsigned int lo = (unsigned int)v;
    unsigned int hi = (unsigned int)(v >> 32);
    lo = __shfl_xor(lo, m, 64);
    hi = __shfl_xor(hi, m, 64);
    return ((u64)hi << 32) | lo;
}

__device__ __forceinline__ unsigned short f2bf(float f) {
    unsigned u = __float_as_uint(f);
    return (unsigned short)((u + 0x7FFFu + ((u >> 16) & 1u)) >> 16);
}

// Workspace layout (bytes):
#define PF_OFF   0u
#define AF_OFF   8388608u
#define INV_OFF  16777216u
#define PCK_OFF  16793600u
#define DONE_OFF 16826368u
#define WS_NEED  16826432u

// Fragment load: frag-block blk, 16-k step kh -> byte blk*65536 + kh*1024 + lane*16.
#define FRAG(base, blk, kh) (*(const bf16x8*)((base) + (((size_t)(blk)) << 16) + ((kh) << 10)))

// fp32 -> bf16 fragment chunk: cid = fb*4096 + kh*64 + lane (16B per chunk).
__device__ __forceinline__ void conv_chunk(const float* __restrict__ x,
                                           unsigned short* __restrict__ Pf,
                                           unsigned short* __restrict__ Af, int cid) {
    const int lane = cid & 63;
    const int kh   = (cid >> 6) & 63;
    const int fb   = cid >> 12;
    const int row  = fb * 32 + (lane & 31);
    const int col  = kh * 16 + (lane >> 5) * 8;

    const float* px = x + (size_t)row * XSTR + col;
    float4 p0 = *(const float4*)(px);
    float4 p1 = *(const float4*)(px + 4);
    float4 a0 = *(const float4*)(px + DDIM);
    float4 a1 = *(const float4*)(px + DDIM + 4);

    u16x8 pv, av;
    pv[0] = f2bf(p0.x); pv[1] = f2bf(p0.y); pv[2] = f2bf(p0.z); pv[3] = f2bf(p0.w);
    pv[4] = f2bf(p1.x); pv[5] = f2bf(p1.y); pv[6] = f2bf(p1.z); pv[7] = f2bf(p1.w);
    av[0] = f2bf(a0.x); av[1] = f2bf(a0.y); av[2] = f2bf(a0.z); av[3] = f2bf(a0.w);
    av[4] = f2bf(a1.x); av[5] = f2bf(a1.y); av[6] = f2bf(a1.z); av[7] = f2bf(a1.w);

    *(u16x8*)(Pf + (size_t)cid * 8) = pv;
    *(u16x8*)(Af + (size_t)cid * 8) = av;
}

// ---- single cooperative kernel: prep + GEMM/argmax + finalize ----
__global__ __launch_bounds__(512, 2) void fused_all(const float* __restrict__ x,
                                                    unsigned short* __restrict__ Pf,
                                                    unsigned short* __restrict__ Af,
                                                    float* __restrict__ inv_an,
                                                    u64* __restrict__ packed,
                                                    float* __restrict__ out) {
    __shared__ int cnt[8];
    cg::grid_group grid = cg::this_grid();

    const int b = blockIdx.x;
    const int t = threadIdx.x;
    const int wave = t >> 6;
    const int lane = t & 63;

    // ---- phase 1a: zero packed (16 rows per block) ----
    if (t < 16) packed[b * 16 + t] = 0ULL;

    // ---- phase 1b: anchor norms (2 rows per wave, coalesced 1KB reads) ----
#pragma unroll
    for (int rr = 0; rr < 2; ++rr) {
        const int row = b * 16 + wave * 2 + rr;
        const float4* a = (const float4*)(x + (size_t)row * XSTR + DDIM);
        float s = 0.0f;
#pragma unroll
        for (int i = 0; i < 4; ++i) {
            float4 v = a[lane + i * 64];
            s += v.x * v.x + v.y * v.y + v.z * v.z + v.w * v.w;
        }
#pragma unroll
        for (int off = 32; off > 0; off >>= 1) s += __shfl_down(s, off, 64);
        if (lane == 0) inv_an[row] = 1.0f / sqrtf(s);
    }

    // ---- phase 1c: fp32 -> bf16 fragment conversion (4 chunks per thread) ----
#pragma unroll
    for (int i = 0; i < 4; ++i) conv_chunk(x, Pf, Af, b * 2048 + i * 512 + t);

    __threadfence();   // release Pf/Af/inv_an/packed device-wide
    grid.sync();
    __threadfence();   // acquire: invalidate potentially-stale L2 lines

    // ---- phase 2: MFMA GEMM + argmax (byte-identical to proven R12 core) ----
    const int bid = b;
    const int xcd = bid & 7;
    const int slt = bid >> 3;                       // 0..31
    const int rblk = (xcd >> 1) * 4 + (slt >> 3);   // 0..15
    const int cblk = (xcd & 1) * 8 + (slt & 7);     // 0..15
    const int r0 = rblk * 256;
    const int c0 = cblk * 256;

    const int l31 = lane & 31;
    const int lh = lane >> 5;
    const int wm = wave & 3;   // m-quarter: rows wm*64..+63
    const int wn = wave >> 2;  // n-half:    cols wn*128..+127

    const int mb0 = rblk * 8 + wm * 2;  // first 32-row frag-block (2 total)
    const int nb0 = cblk * 8 + wn * 4;  // first 32-col frag-block (4 total)

    const char* pP = (const char*)Pf + (size_t)lane * 16 + ((size_t)mb0 << 16);
    const char* pA = (const char*)Af + (size_t)lane * 16 + ((size_t)nb0 << 16);

    f32x16 zero16 = {0.f,0.f,0.f,0.f,0.f,0.f,0.f,0.f,0.f,0.f,0.f,0.f,0.f,0.f,0.f,0.f};
    f32x16 acc[2][4];
#pragma unroll
    for (int i = 0; i < 2; ++i)
#pragma unroll
        for (int j = 0; j < 4; ++j) acc[i][j] = zero16;

    // 3-set rotating register pipeline
    bf16x8 ph[3][2], aa[3][4];
#pragma unroll
    for (int q = 0; q < 2; ++q) { ph[0][q] = FRAG(pP, q, 0); ph[1][q] = FRAG(pP, q, 1); }
#pragma unroll
    for (int q = 0; q < 4; ++q) { aa[0][q] = FRAG(pA, q, 0); aa[1][q] = FRAG(pA, q, 1); }

#pragma unroll
    for (int kh = 0; kh < 64; ++kh) {
        const int cs = kh % 3;
        if (kh + 2 < 64) {
            const int ns = (kh + 2) % 3;
#pragma unroll
            for (int q = 0; q < 2; ++q) ph[ns][q] = FRAG(pP, q, kh + 2);
#pragma unroll
            for (int q = 0; q < 4; ++q) aa[ns][q] = FRAG(pA, q, kh + 2);
        }
#pragma unroll
        for (int mt = 0; mt < 2; ++mt)
#pragma unroll
            for (int nt = 0; nt < 4; ++nt)
                acc[mt][nt] = __builtin_amdgcn_mfma_f32_32x32x16_bf16(ph[cs][mt], aa[cs][nt], acc[mt][nt], 0, 0, 0);
    }

    // ---- epilogue: scale by inv_an, packed argmax ----
    float ian[4];
#pragma unroll
    for (int nt = 0; nt < 4; ++nt) ian[nt] = inv_an[c0 + wn * 128 + nt * 32 + l31];

    // 32x32 C/D layout (m74/m101): col = lane&31, row = (reg&3)+8*(reg>>2)+4*(lane>>5)
#pragma unroll
    for (int mt = 0; mt < 2; ++mt)
#pragma unroll
        for (int reg = 0; reg < 16; ++reg) {
            const int row = r0 + wm * 64 + mt * 32 + (reg & 3) + 8 * (reg >> 2) + 4 * lh;
            u64 best = 0ULL;
#pragma unroll
            for (int nt = 0; nt < 4; ++nt) {
                const int col = c0 + wn * 128 + nt * 32 + l31;
                const float v = acc[mt][nt][reg] * ian[nt];
                const u64 p = ((u64)fkey(v) << 32) | (unsigned int)(~col);
                best = best > p ? best : p;
            }
#pragma unroll
            for (int m = 1; m <= 16; m <<= 1) {
                const u64 o = shfl_xor_u64(best, m);
                best = best > o ? best : o;
            }
            if (l31 == 0) atomicMax(&packed[row], best);
        }

    // ---- phase 3: finalize ----
    __threadfence();   // publish atomicMax results
    grid.sync();
    if (b == 0) {
        __threadfence();
        int c = 0;
        for (int r = t; r < NROWS; r += 512) {
            u64 v = atomicAdd(&packed[r], 0ULL);  // device-coherent read
            unsigned int col = ~(unsigned int)(v & 0xFFFFFFFFULL);
            c += (col == (unsigned int)r) ? 1 : 0;
        }
#pragma unroll
        for (int off = 32; off > 0; off >>= 1) c += __shfl_down(c, off, 64);
        if (lane == 0) cnt[wave] = c;
        __syncthreads();
        if (t == 0) {
            int tot = 0;
#pragma unroll
            for (int w = 0; w < 8; ++w) tot += cnt[w];
            out[0] = 1.0f;  // exp(temploss - stop_gradient(temploss)) == 1 exactly
            out[1] = 100.0f * (float)tot / (float)NROWS;
        }
    }
}

// ---------------- non-cooperative bf16 path (R13, fallback if coop fails) ----------------
__global__ __launch_bounds__(256) void norms2_kernel(const float* __restrict__ x,
                                                     float* __restrict__ inv_an,
                                                     u64* __restrict__ packed,
                                                     unsigned int* __restrict__ done) {
    int gid  = blockIdx.x * 256 + threadIdx.x;
    int j    = gid >> 6;
    int lane = threadIdx.x & 63;
    if (gid < NROWS) packed[gid] = 0ULL;
    if (gid == 0) *done = 0u;
    const float4* a = (const float4*)(x + (size_t)j * XSTR + DDIM);
    float s = 0.0f;
#pragma unroll
    for (int i = 0; i < 4; ++i) {
        float4 v = a[lane + i * 64];
        s += v.x * v.x + v.y * v.y + v.z * v.z + v.w * v.w;
    }
#pragma unroll
    for (int off = 32; off > 0; off >>= 1) s += __shfl_down(s, off, 64);
    if (lane == 0) inv_an[j] = 1.0f / sqrtf(s);
}

__global__ __launch_bounds__(256) void conv_kernel(const float* __restrict__ x,
                                                   unsigned short* __restrict__ Pf,
                                                   unsigned short* __restrict__ Af) {
    const int cid = blockIdx.x * 256 + threadIdx.x;
    conv_chunk(x, Pf, Af, cid);
}

__global__ __launch_bounds__(512, 2) void mfma_gemm_argmax(const unsigned short* __restrict__ Pf,
                                                           const unsigned short* __restrict__ Af,
                                                           const float* __restrict__ inv_an,
                                                           u64* __restrict__ packed,
                                                           unsigned int* __restrict__ done,
                                                           float* __restrict__ out) {
    __shared__ unsigned int lastflag;
    __shared__ int cnt[8];

    const int bid = blockIdx.x;
    const int xcd = bid & 7;
    const int slt = bid >> 3;
    const int rblk = (xcd >> 1) * 4 + (slt >> 3);
    const int cblk = (xcd & 1) * 8 + (slt & 7);
    const int r0 = rblk * 256;
    const int c0 = cblk * 256;

    const int wave = threadIdx.x >> 6;
    const int lane = threadIdx.x & 63;
    const int l31 = lane & 31;
    const int lh = lane >> 5;
    const int wm = wave & 3;
    const int wn = wave >> 2;

    const int mb0 = rblk * 8 + wm * 2;
    const int nb0 = cblk * 8 + wn * 4;

    const char* pP = (const char*)Pf + (size_t)lane * 16 + ((size_t)mb0 << 16);
    const char* pA = (const char*)Af + (size_t)lane * 16 + ((size_t)nb0 << 16);

    f32x16 zero16 = {0.f,0.f,0.f,0.f,0.f,0.f,0.f,0.f,0.f,0.f,0.f,0.f,0.f,0.f,0.f,0.f};
    f32x16 acc[2][4];
#pragma unroll
    for (int i = 0; i < 2; ++i)
#pragma unroll
        for (int j = 0; j < 4; ++j) acc[i][j] = zero16;

    bf16x8 ph[3][2], aa[3][4];
#pragma unroll
    for (int q = 0; q < 2; ++q) { ph[0][q] = FRAG(pP, q, 0); ph[1][q] = FRAG(pP, q, 1); }
#pragma unroll
    for (int q = 0; q < 4; ++q) { aa[0][q] = FRAG(pA, q, 0); aa[1][q] = FRAG(pA, q, 1); }

#pragma unroll
    for (int kh = 0; kh < 64; ++kh) {
        const int cs = kh % 3;
        if (kh + 2 < 64) {
            const int ns = (kh + 2) % 3;
#pragma unroll
            for (int q = 0; q < 2; ++q) ph[ns][q] = FRAG(pP, q, kh + 2);
#pragma unroll
            for (int q = 0; q < 4; ++q) aa[ns][q] = FRAG(pA, q, kh + 2);
        }
#pragma unroll
        for (int mt = 0; mt < 2; ++mt)
#pragma unroll
            for (int nt = 0; nt < 4; ++nt)
                acc[mt][nt] = __builtin_amdgcn_mfma_f32_32x32x16_bf16(ph[cs][mt], aa[cs][nt], acc[mt][nt], 0, 0, 0);
    }

    float ian[4];
#pragma unroll
    for (int nt = 0; nt < 4; ++nt) ian[nt] = inv_an[c0 + wn * 128 + nt * 32 + l31];

#pragma unroll
    for (int mt = 0; mt < 2; ++mt)
#pragma unroll
        for (int reg = 0; reg < 16; ++reg) {
            const int row = r0 + wm * 64 + mt * 32 + (reg & 3) + 8 * (reg >> 2) + 4 * lh;
            u64 best = 0ULL;
#pragma unroll
            for (int nt = 0; nt < 4; ++nt) {
                const int col = c0 + wn * 128 + nt * 32 + l31;
                const float v = acc[mt][nt][reg] * ian[nt];
                const u64 p = ((u64)fkey(v) << 32) | (unsigned int)(~col);
                best = best > p ? best : p;
            }
#pragma unroll
            for (int m = 1; m <= 16; m <<= 1) {
                const u64 o = shfl_xor_u64(best, m);
                best = best > o ? best : o;
            }
            if (l31 == 0) atomicMax(&packed[row], best);
        }

    __syncthreads();
    if (threadIdx.x == 0) {
        __threadfence();
        unsigned int old = atomicAdd(done, 1u);
        lastflag = (old == 255u) ? 1u : 0u;
    }
    __syncthreads();
    if (lastflag) {
        int c = 0;
        for (int r = threadIdx.x; r < NROWS; r += 512) {
            u64 v = atomicAdd(&packed[r], 0ULL);
            unsigned int col = ~(unsigned int)(v & 0xFFFFFFFFULL);
            c += (col == (unsigned int)r) ? 1 : 0;
        }
#pragma unroll
        for (int off = 32; off > 0; off >>= 1) c += __shfl_down(c, off, 64);
        if ((threadIdx.x & 63) == 0) cnt[threadIdx.x >> 6] = c;
        __syncthreads();
        if (threadIdx.x == 0) {
            int tot = 0;
#pragma unroll
            for (int w = 0; w < 8; ++w) tot += cnt[w];
            out[0] = 1.0f;
            out[1] = 100.0f * (float)tot / (float)NROWS;
        }
    }
}

// ---------------- fallback fp32 path (proven R1) ----------------
__global__ __launch_bounds__(256) void norms_kernel(const float* __restrict__ x,
                                                    float* __restrict__ inv_an,
                                                    u64* __restrict__ packed) {
    int gid  = blockIdx.x * 256 + threadIdx.x;
    int j    = gid >> 6;
    int lane = threadIdx.x & 63;
    if (gid < NROWS) packed[gid] = 0ULL;
    const float4* a = (const float4*)(x + (size_t)j * XSTR + DDIM);
    float s = 0.0f;
#pragma unroll
    for (int i = 0; i < 4; ++i) {
        float4 v = a[lane + i * 64];
        s += v.x * v.x + v.y * v.y + v.z * v.z + v.w * v.w;
    }
#pragma unroll
    for (int off = 32; off > 0; off >>= 1) s += __shfl_down(s, off, 64);
    if (lane == 0) inv_an[j] = 1.0f / sqrtf(s);
}

__global__ __launch_bounds__(256) void gemm_argmax_kernel(const float* __restrict__ x,
                                                          const float* __restrict__ inv_an,
                                                          u64* __restrict__ packed) {
    __shared__ __align__(16) float Pt[16][128];
    __shared__ __align__(16) float At[16][128];
    const int r0 = blockIdx.x * 128;
    const int c0 = blockIdx.y * 128;
    const int t = threadIdx.x;
    const int tx = t & 15;
    const int ty = t >> 4;
    const int srow = t >> 1;
    const int skq = (t & 1) * 8;
    float acc[8][8];
#pragma unroll
    for (int r = 0; r < 8; ++r)
#pragma unroll
        for (int c = 0; c < 8; ++c) acc[r][c] = 0.0f;
    const float* gp = x + (size_t)(r0 + srow) * XSTR + skq;
    const float* ga = x + (size_t)(c0 + srow) * XSTR + DDIM + skq;
    for (int k0 = 0; k0 < DDIM; k0 += 16) {
        __syncthreads();
        float4 p0 = *(const float4*)(gp + k0);
        float4 p1 = *(const float4*)(gp + k0 + 4);
        float4 a0 = *(const float4*)(ga + k0);
        float4 a1 = *(const float4*)(ga + k0 + 4);
        Pt[skq + 0][srow] = p0.x; Pt[skq + 1][srow] = p0.y;
        Pt[skq + 2][srow] = p0.z; Pt[skq + 3][srow] = p0.w;
        Pt[skq + 4][srow] = p1.x; Pt[skq + 5][srow] = p1.y;
        Pt[skq + 6][srow] = p1.z; Pt[skq + 7][srow] = p1.w;
        At[skq + 0][srow] = a0.x; At[skq + 1][srow] = a0.y;
        At[skq + 2][srow] = a0.z; At[skq + 3][srow] = a0.w;
        At[skq + 4][srow] = a1.x; At[skq + 5][srow] = a1.y;
        At[skq + 6][srow] = a1.z; At[skq + 7][srow] = a1.w;
        __syncthreads();
#pragma unroll
        for (int kk = 0; kk < 16; ++kk) {
            float pr[8], ar[8];
            *(float4*)&pr[0] = *(const float4*)&Pt[kk][ty * 8];
            *(float4*)&pr[4] = *(const float4*)&Pt[kk][ty * 8 + 4];
            *(float4*)&ar[0] = *(const float4*)&At[kk][tx * 8];
            *(float4*)&ar[4] = *(const float4*)&At[kk][tx * 8 + 4];
#pragma unroll
            for (int r = 0; r < 8; ++r)
#pragma unroll
                for (int c = 0; c < 8; ++c) acc[r][c] += pr[r] * ar[c];
        }
    }
    float ian[8];
#pragma unroll
    for (int c = 0; c < 8; ++c) ian[c] = inv_an[c0 + tx * 8 + c];
#pragma unroll
    for (int r = 0; r < 8; ++r) {
        int row = r0 + ty * 8 + r;
        u64 best = 0ULL;
#pragma unroll
        for (int c = 0; c < 8; ++c) {
            int col = c0 + tx * 8 + c;
            float v = acc[r][c] * ian[c];
            u64 p = ((u64)fkey(v) << 32) | (unsigned int)(~col);
            best = best > p ? best : p;
        }
#pragma unroll
        for (int m = 1; m <= 8; m <<= 1) {
            u64 o = shfl_xor_u64(best, m);
            best = best > o ? best : o;
        }
        if (tx == 0) atomicMax(&packed[row], best);
    }
}

__global__ __launch_bounds__(256) void finalize_kernel(const u64* __restrict__ packed,
                                                       float* __restrict__ out) {
    __shared__ int cnt_s;
    int t = threadIdx.x;
    if (t == 0) cnt_s = 0;
    __syncthreads();
    int c = 0;
    for (int r = t; r < NROWS; r += 256) {
        unsigned int col = ~(unsigned int)(packed[r] & 0xFFFFFFFFULL);
        c += (col == (unsigned int)r) ? 1 : 0;
    }
#pragma unroll
    for (int off = 32; off > 0; off >>= 1) c += __shfl_down(c, off, 64);
    if ((t & 63) == 0) atomicAdd(&cnt_s, c);
    __syncthreads();
    if (t == 0) {
        out[0] = 1.0f;
        out[1] = 100.0f * (float)cnt_s / (float)NROWS;
    }
}

extern "C" void kernel_launch(void* const* d_in, const int* in_sizes, int n_in,
                              void* d_out, int out_size, void* d_ws, size_t ws_size,
                              hipStream_t stream) {
    (void)in_sizes; (void)n_in; (void)out_size;
    const float* x = (const float*)d_in[0];
    float* out = (float*)d_out;

    if (ws_size >= (size_t)WS_NEED) {
        char* ws = (char*)d_ws;
        unsigned short* Pf = (unsigned short*)(ws + PF_OFF);
        unsigned short* Af = (unsigned short*)(ws + AF_OFF);
        float* inv_an = (float*)(ws + INV_OFF);
        u64* packed = (u64*)(ws + PCK_OFF);
        unsigned int* done = (unsigned int*)(ws + DONE_OFF);

        void* args[] = {(void*)&x, (void*)&Pf, (void*)&Af,
                        (void*)&inv_an, (void*)&packed, (void*)&out};
        hipError_t e = hipLaunchCooperativeKernel((void*)fused_all, dim3(256), dim3(512),
                                                  args, 0, stream);
        if (e != hipSuccess) {
            // cooperative launch unavailable (e.g. under capture) -> 3-kernel path
            norms2_kernel<<<NROWS / 4, 256, 0, stream>>>(x, inv_an, packed, done);
            conv_kernel<<<2048, 256, 0, stream>>>(x, Pf, Af);
            mfma_gemm_argmax<<<256, 512, 0, stream>>>(Pf, Af, inv_an, packed, done, out);
        }
    } else {
        float* inv_an = (float*)d_ws;
        u64* packed = (u64*)((char*)d_ws + NROWS * sizeof(float));
        norms_kernel<<<NROWS / 4, 256, 0, stream>>>(x, inv_an, packed);
        dim3 grid(NROWS / 128, NROWS / 128);
        gemm_argmax_kernel<<<grid, 256, 0, stream>>>(x, inv_an, packed);
        finalize_kernel<<<1, 256, 0, stream>>>(packed, out);
    }
}

// Round 3
// 123.325 us; speedup vs baseline: 2.6592x; 2.6592x over previous
//
#include <hip/hip_runtime.h>

// x (4096, 2, 1024) fp32.  P_i = x[i,0,:], A_j = x[i,1,:]
// out[0] = 1.0 exactly; out[1] = prec1 = 100*mean(argmax_j sim[i,j] == i)
// argmax_j sim[i,j] == argmax_j dot(P_i,A_j)*inv_norm(A_j).
// R15: cooperative fusion (R14) reverted -- single-dispatch run proved the
// ~60us gap is FIXED harness overhead (328 total vs 260 kernel), and the
// threadfence/grid.sync L2 writeback wrecked locality (MfmaUtil 5%).
// This round attacks the 58us GEMM itself (was register-direct from L2,
// 3MB/block redundant reads, latency-bound, MfmaUtil 22%):
// T3/T4-style LDS-staged pipeline. BK=64, double-buffered 128KB LDS,
// global_load_lds (16B) staging in fragment order (lane-order => linear LDS,
// no swizzle needed), per-kh phases {6 ds_read || 2 stage -> barrier ->
// lgkmcnt(0) -> 8 MFMA (setprio-wrapped) -> barrier}; the only vmcnt(0)
// sits one full K-tile (~2200cyc) after load issue => drains with slack.
// Frag-order map (R4/R9/R11-verified): block fb region = 64KB at fb*65536;
// byte = kh*1024 + lane*16 -> (row = fb*32 + (lane&31), k = kh*16+(lane>>5)*8..+8).

#define NROWS 4096
#define DDIM  1024
#define XSTR  2048

typedef unsigned int u32;
typedef unsigned long long u64;
typedef __attribute__((ext_vector_type(8))) short bf16x8;
typedef __attribute__((ext_vector_type(8))) unsigned short u16x8;
typedef __attribute__((ext_vector_type(16))) float f32x16;

__device__ __forceinline__ unsigned int fkey(float f) {
    unsigned int u = __float_as_uint(f);
    return (u & 0x80000000u) ? ~u : (u | 0x80000000u);
}

__device__ __forceinline__ u64 shfl_xor_u64(u64 v, int m) {
    unsigned int lo = (unsigned int)v;
    unsigned int hi = (unsigned int)(v >> 32);
    lo = __shfl_xor(lo, m, 64);
    hi = __shfl_xor(hi, m, 64);
    return ((u64)hi << 32) | lo;
}

__device__ __forceinline__ unsigned short f2bf(float f) {
    unsigned u = __float_as_uint(f);
    return (unsigned short)((u + 0x7FFFu + ((u >> 16) & 1u)) >> 16);
}

// Workspace layout (bytes):
#define PF_OFF   0u
#define AF_OFF   8388608u
#define INV_OFF  16777216u
#define PCK_OFF  16793600u
#define DONE_OFF 16826368u
#define WS_NEED  16826432u

// ---- prep: norms (one wave per row, coalesced) + zero packed/done ----
__global__ __launch_bounds__(256) void norms2_kernel(const float* __restrict__ x,
                                                     float* __restrict__ inv_an,
                                                     u64* __restrict__ packed,
                                                     unsigned int* __restrict__ done) {
    int gid  = blockIdx.x * 256 + threadIdx.x;
    int j    = gid >> 6;
    int lane = threadIdx.x & 63;
    if (gid < NROWS) packed[gid] = 0ULL;
    if (gid == 0) *done = 0u;
    const float4* a = (const float4*)(x + (size_t)j * XSTR + DDIM);
    float s = 0.0f;
#pragma unroll
    for (int i = 0; i < 4; ++i) {
        float4 v = a[lane + i * 64];
        s += v.x * v.x + v.y * v.y + v.z * v.z + v.w * v.w;
    }
#pragma unroll
    for (int off = 32; off > 0; off >>= 1) s += __shfl_down(s, off, 64);
    if (lane == 0) inv_an[j] = 1.0f / sqrtf(s);
}

// ---- prep: fp32 -> bf16 fragment conversion, one thread per 16B chunk ----
// cid = fb*4096 + kh*64 + lane; coalesced 16B writes; full-occupancy MLP.
__global__ __launch_bounds__(256) void conv_kernel(const float* __restrict__ x,
                                                   unsigned short* __restrict__ Pf,
                                                   unsigned short* __restrict__ Af) {
    const int cid  = blockIdx.x * 256 + threadIdx.x;
    const int lane = cid & 63;
    const int kh   = (cid >> 6) & 63;
    const int fb   = cid >> 12;
    const int row  = fb * 32 + (lane & 31);
    const int col  = kh * 16 + (lane >> 5) * 8;

    const float* px = x + (size_t)row * XSTR + col;
    float4 p0 = *(const float4*)(px);
    float4 p1 = *(const float4*)(px + 4);
    float4 a0 = *(const float4*)(px + DDIM);
    float4 a1 = *(const float4*)(px + DDIM + 4);

    u16x8 pv, av;
    pv[0] = f2bf(p0.x); pv[1] = f2bf(p0.y); pv[2] = f2bf(p0.z); pv[3] = f2bf(p0.w);
    pv[4] = f2bf(p1.x); pv[5] = f2bf(p1.y); pv[6] = f2bf(p1.z); pv[7] = f2bf(p1.w);
    av[0] = f2bf(a0.x); av[1] = f2bf(a0.y); av[2] = f2bf(a0.z); av[3] = f2bf(a0.w);
    av[4] = f2bf(a1.x); av[5] = f2bf(a1.y); av[6] = f2bf(a1.z); av[7] = f2bf(a1.w);

    *(u16x8*)(Pf + (size_t)cid * 8) = pv;
    *(u16x8*)(Af + (size_t)cid * 8) = av;
}

// ---- MFMA GEMM + argmax + fused finalize, LDS-staged T3/T4 pipeline ----
// 256x256 block tile, 8 waves (4m x 2n) of 64x128. Grid 256, XCD-swizzled.
// LDS per buffer (64KB): [P: kh_l*8KB + fb_l*1KB] [A: +32KB, same]; x2 dbuf.
// Wave w stages fb_l=w for both P and A (2 gload_lds per phase).
__global__ __launch_bounds__(512, 2) void mfma_gemm_argmax(const unsigned short* __restrict__ Pf,
                                                           const unsigned short* __restrict__ Af,
                                                           const float* __restrict__ inv_an,
                                                           u64* __restrict__ packed,
                                                           unsigned int* __restrict__ done,
                                                           float* __restrict__ out) {
    __shared__ __align__(16) unsigned int lds[32768];  // 128 KB, 2 x 64KB buffers
    __shared__ unsigned int lastflag;
    __shared__ int cnt[8];

    const int bid = blockIdx.x;
    const int xcd = bid & 7;
    const int slt = bid >> 3;                       // 0..31
    const int rblk = (xcd >> 1) * 4 + (slt >> 3);   // 0..15
    const int cblk = (xcd & 1) * 8 + (slt & 7);     // 0..15
    const int r0 = rblk * 256;
    const int c0 = cblk * 256;

    const int wave = threadIdx.x >> 6;  // 0..7
    const int lane = threadIdx.x & 63;
    const int l31 = lane & 31;
    const int lh = lane >> 5;
    const int wm = wave & 3;   // m-quarter: rows wm*64..+63
    const int wn = wave >> 2;  // n-half:    cols wn*128..+127

    // per-wave global stage pointers: wave stages frag-block fb_l = wave
    const char* gPs = (const char*)Pf + (((size_t)(rblk * 8 + wave)) << 16) + (size_t)lane * 16;
    const char* gAs = (const char*)Af + (((size_t)(cblk * 8 + wave)) << 16) + (size_t)lane * 16;

    f32x16 zero16 = {0.f,0.f,0.f,0.f,0.f,0.f,0.f,0.f,0.f,0.f,0.f,0.f,0.f,0.f,0.f,0.f};
    f32x16 acc[2][4];
#pragma unroll
    for (int i = 0; i < 2; ++i)
#pragma unroll
        for (int j = 0; j < 4; ++j) acc[i][j] = zero16;

    // ---- prologue: stage tile 0 into buffer 0 (8 loads per wave) ----
#pragma unroll
    for (int kh_l = 0; kh_l < 4; ++kh_l) {
        __builtin_amdgcn_global_load_lds((const u32*)(gPs + ((size_t)kh_l << 10)),
                                         &lds[kh_l * 2048 + wave * 256], 16, 0, 0);
        __builtin_amdgcn_global_load_lds((const u32*)(gAs + ((size_t)kh_l << 10)),
                                         &lds[8192 + kh_l * 2048 + wave * 256], 16, 0, 0);
    }

    // ---- K loop: 16 tiles of BK=64 (4 kh phases each) ----
    for (int t = 0; t < 16; ++t) {
        const int cb = t & 1;
        const int nbuf = (cb ^ 1) * 16384;
        const int cbuf = cb * 16384;

        // tile-t data landed everywhere (my 8 loads issued one full tile ago)
        asm volatile("s_waitcnt vmcnt(0)" ::: "memory");
        __builtin_amdgcn_s_barrier();
        __builtin_amdgcn_sched_barrier(0);

#pragma unroll
        for (int kh_l = 0; kh_l < 4; ++kh_l) {
            // ds_read this phase's 6 fragments (linear, conflict-free)
            const u32* bp = &lds[cbuf + kh_l * 2048 + (wm * 2) * 256 + lane * 4];
            bf16x8 f_p0 = *(const bf16x8*)(bp);
            bf16x8 f_p1 = *(const bf16x8*)(bp + 256);
            const u32* ba = &lds[cbuf + 8192 + kh_l * 2048 + (wn * 4) * 256 + lane * 4];
            bf16x8 f_a0 = *(const bf16x8*)(ba);
            bf16x8 f_a1 = *(const bf16x8*)(ba + 256);
            bf16x8 f_a2 = *(const bf16x8*)(ba + 512);
            bf16x8 f_a3 = *(const bf16x8*)(ba + 768);

            // issue 2 stage loads of tile t+1 (land by next tile's vmcnt)
            if (t + 1 < 16) {
                const size_t go = ((size_t)((t + 1) * 4 + kh_l)) << 10;
                __builtin_amdgcn_global_load_lds((const u32*)(gPs + go),
                                                 &lds[nbuf + kh_l * 2048 + wave * 256], 16, 0, 0);
                __builtin_amdgcn_global_load_lds((const u32*)(gAs + go),
                                                 &lds[nbuf + 8192 + kh_l * 2048 + wave * 256], 16, 0, 0);
            }

            __builtin_amdgcn_s_barrier();
            asm volatile("s_waitcnt lgkmcnt(0)" ::: "memory");
            __builtin_amdgcn_sched_barrier(0);
            __builtin_amdgcn_s_setprio(1);
            acc[0][0] = __builtin_amdgcn_mfma_f32_32x32x16_bf16(f_p0, f_a0, acc[0][0], 0, 0, 0);
            acc[0][1] = __builtin_amdgcn_mfma_f32_32x32x16_bf16(f_p0, f_a1, acc[0][1], 0, 0, 0);
            acc[0][2] = __builtin_amdgcn_mfma_f32_32x32x16_bf16(f_p0, f_a2, acc[0][2], 0, 0, 0);
            acc[0][3] = __builtin_amdgcn_mfma_f32_32x32x16_bf16(f_p0, f_a3, acc[0][3], 0, 0, 0);
            acc[1][0] = __builtin_amdgcn_mfma_f32_32x32x16_bf16(f_p1, f_a0, acc[1][0], 0, 0, 0);
            acc[1][1] = __builtin_amdgcn_mfma_f32_32x32x16_bf16(f_p1, f_a1, acc[1][1], 0, 0, 0);
            acc[1][2] = __builtin_amdgcn_mfma_f32_32x32x16_bf16(f_p1, f_a2, acc[1][2], 0, 0, 0);
            acc[1][3] = __builtin_amdgcn_mfma_f32_32x32x16_bf16(f_p1, f_a3, acc[1][3], 0, 0, 0);
            __builtin_amdgcn_s_setprio(0);
            __builtin_amdgcn_s_barrier();
        }
    }

    // ---- epilogue: scale by inv_an, packed argmax ----
    float ian[4];
#pragma unroll
    for (int nt = 0; nt < 4; ++nt) ian[nt] = inv_an[c0 + wn * 128 + nt * 32 + l31];

    // 32x32 C/D layout (m74/m101): col = lane&31, row = (reg&3)+8*(reg>>2)+4*(lane>>5)
#pragma unroll
    for (int mt = 0; mt < 2; ++mt)
#pragma unroll
        for (int reg = 0; reg < 16; ++reg) {
            const int row = r0 + wm * 64 + mt * 32 + (reg & 3) + 8 * (reg >> 2) + 4 * lh;
            u64 best = 0ULL;
#pragma unroll
            for (int nt = 0; nt < 4; ++nt) {
                const int col = c0 + wn * 128 + nt * 32 + l31;
                const float v = acc[mt][nt][reg] * ian[nt];
                const u64 p = ((u64)fkey(v) << 32) | (unsigned int)(~col);
                best = best > p ? best : p;
            }
#pragma unroll
            for (int m = 1; m <= 16; m <<= 1) {
                const u64 o = shfl_xor_u64(best, m);
                best = best > o ? best : o;
            }
            if (l31 == 0) atomicMax(&packed[row], best);
        }

    // ---- fused finalize: last block counts and writes out ----
    __syncthreads();
    if (threadIdx.x == 0) {
        __threadfence();  // publish this block's atomicMax results
        unsigned int old = atomicAdd(done, 1u);
        lastflag = (old == 255u) ? 1u : 0u;
    }
    __syncthreads();
    if (lastflag) {
        int c = 0;
        for (int r = threadIdx.x; r < NROWS; r += 512) {
            u64 v = atomicAdd(&packed[r], 0ULL);  // device-coherent read
            unsigned int col = ~(unsigned int)(v & 0xFFFFFFFFULL);
            c += (col == (unsigned int)r) ? 1 : 0;
        }
#pragma unroll
        for (int off = 32; off > 0; off >>= 1) c += __shfl_down(c, off, 64);
        if ((threadIdx.x & 63) == 0) cnt[threadIdx.x >> 6] = c;
        __syncthreads();
        if (threadIdx.x == 0) {
            int tot = 0;
#pragma unroll
            for (int w = 0; w < 8; ++w) tot += cnt[w];
            out[0] = 1.0f;  // exp(temploss - stop_gradient(temploss)) == 1 exactly
            out[1] = 100.0f * (float)tot / (float)NROWS;
        }
    }
}

// ---------------- fallback fp32 path (proven R1) ----------------
__global__ __launch_bounds__(256) void norms_kernel(const float* __restrict__ x,
                                                    float* __restrict__ inv_an,
                                                    u64* __restrict__ packed) {
    int gid  = blockIdx.x * 256 + threadIdx.x;
    int j    = gid >> 6;
    int lane = threadIdx.x & 63;
    if (gid < NROWS) packed[gid] = 0ULL;
    const float4* a = (const float4*)(x + (size_t)j * XSTR + DDIM);
    float s = 0.0f;
#pragma unroll
    for (int i = 0; i < 4; ++i) {
        float4 v = a[lane + i * 64];
        s += v.x * v.x + v.y * v.y + v.z * v.z + v.w * v.w;
    }
#pragma unroll
    for (int off = 32; off > 0; off >>= 1) s += __shfl_down(s, off, 64);
    if (lane == 0) inv_an[j] = 1.0f / sqrtf(s);
}

__global__ __launch_bounds__(256) void gemm_argmax_kernel(const float* __restrict__ x,
                                                          const float* __restrict__ inv_an,
                                                          u64* __restrict__ packed) {
    __shared__ __align__(16) float Pt[16][128];
    __shared__ __align__(16) float At[16][128];
    const int r0 = blockIdx.x * 128;
    const int c0 = blockIdx.y * 128;
    const int t = threadIdx.x;
    const int tx = t & 15;
    const int ty = t >> 4;
    const int srow = t >> 1;
    const int skq = (t & 1) * 8;
    float acc[8][8];
#pragma unroll
    for (int r = 0; r < 8; ++r)
#pragma unroll
        for (int c = 0; c < 8; ++c) acc[r][c] = 0.0f;
    const float* gp = x + (size_t)(r0 + srow) * XSTR + skq;
    const float* ga = x + (size_t)(c0 + srow) * XSTR + DDIM + skq;
    for (int k0 = 0; k0 < DDIM; k0 += 16) {
        __syncthreads();
        float4 p0 = *(const float4*)(gp + k0);
        float4 p1 = *(const float4*)(gp + k0 + 4);
        float4 a0 = *(const float4*)(ga + k0);
        float4 a1 = *(const float4*)(ga + k0 + 4);
        Pt[skq + 0][srow] = p0.x; Pt[skq + 1][srow] = p0.y;
        Pt[skq + 2][srow] = p0.z; Pt[skq + 3][srow] = p0.w;
        Pt[skq + 4][srow] = p1.x; Pt[skq + 5][srow] = p1.y;
        Pt[skq + 6][srow] = p1.z; Pt[skq + 7][srow] = p1.w;
        At[skq + 0][srow] = a0.x; At[skq + 1][srow] = a0.y;
        At[skq + 2][srow] = a0.z; At[skq + 3][srow] = a0.w;
        At[skq + 4][srow] = a1.x; At[skq + 5][srow] = a1.y;
        At[skq + 6][srow] = a1.z; At[skq + 7][srow] = a1.w;
        __syncthreads();
#pragma unroll
        for (int kk = 0; kk < 16; ++kk) {
            float pr[8], ar[8];
            *(float4*)&pr[0] = *(const float4*)&Pt[kk][ty * 8];
            *(float4*)&pr[4] = *(const float4*)&Pt[kk][ty * 8 + 4];
            *(float4*)&ar[0] = *(const float4*)&At[kk][tx * 8];
            *(float4*)&ar[4] = *(const float4*)&At[kk][tx * 8 + 4];
#pragma unroll
            for (int r = 0; r < 8; ++r)
#pragma unroll
                for (int c = 0; c < 8; ++c) acc[r][c] += pr[r] * ar[c];
        }
    }
    float ian[8];
#pragma unroll
    for (int c = 0; c < 8; ++c) ian[c] = inv_an[c0 + tx * 8 + c];
#pragma unroll
    for (int r = 0; r < 8; ++r) {
        int row = r0 + ty * 8 + r;
        u64 best = 0ULL;
#pragma unroll
        for (int c = 0; c < 8; ++c) {
            int col = c0 + tx * 8 + c;
            float v = acc[r][c] * ian[c];
            u64 p = ((u64)fkey(v) << 32) | (unsigned int)(~col);
            best = best > p ? best : p;
        }
#pragma unroll
        for (int m = 1; m <= 8; m <<= 1) {
            u64 o = shfl_xor_u64(best, m);
            best = best > o ? best : o;
        }
        if (tx == 0) atomicMax(&packed[row], best);
    }
}

__global__ __launch_bounds__(256) void finalize_kernel(const u64* __restrict__ packed,
                                                       float* __restrict__ out) {
    __shared__ int cnt_s;
    int t = threadIdx.x;
    if (t == 0) cnt_s = 0;
    __syncthreads();
    int c = 0;
    for (int r = t; r < NROWS; r += 256) {
        unsigned int col = ~(unsigned int)(packed[r] & 0xFFFFFFFFULL);
        c += (col == (unsigned int)r) ? 1 : 0;
    }
#pragma unroll
    for (int off = 32; off > 0; off >>= 1) c += __shfl_down(c, off, 64);
    if ((t & 63) == 0) atomicAdd(&cnt_s, c);
    __syncthreads();
    if (t == 0) {
        out[0] = 1.0f;
        out[1] = 100.0f * (float)cnt_s / (float)NROWS;
    }
}

extern "C" void kernel_launch(void* const* d_in, const int* in_sizes, int n_in,
                              void* d_out, int out_size, void* d_ws, size_t ws_size,
                              hipStream_t stream) {
    (void)in_sizes; (void)n_in; (void)out_size;
    const float* x = (const float*)d_in[0];
    float* out = (float*)d_out;

    if (ws_size >= (size_t)WS_NEED) {
        char* ws = (char*)d_ws;
        unsigned short* Pf = (unsigned short*)(ws + PF_OFF);
        unsigned short* Af = (unsigned short*)(ws + AF_OFF);
        float* inv_an = (float*)(ws + INV_OFF);
        u64* packed = (u64*)(ws + PCK_OFF);
        unsigned int* done = (unsigned int*)(ws + DONE_OFF);

        norms2_kernel<<<NROWS / 4, 256, 0, stream>>>(x, inv_an, packed, done);
        conv_kernel<<<2048, 256, 0, stream>>>(x, Pf, Af);
        mfma_gemm_argmax<<<256, 512, 0, stream>>>(Pf, Af, inv_an, packed, done, out);
    } else {
        float* inv_an = (float*)d_ws;
        u64* packed = (u64*)((char*)d_ws + NROWS * sizeof(float));
        norms_kernel<<<NROWS / 4, 256, 0, stream>>>(x, inv_an, packed);
        dim3 grid(NROWS / 128, NROWS / 128);
        gemm_argmax_kernel<<<grid, 256, 0, stream>>>(x, inv_an, packed);
        finalize_kernel<<<1, 256, 0, stream>>>(packed, out);
    }
}

// Round 5
// 123.317 us; speedup vs baseline: 2.6594x; 1.0001x over previous
//
#include <hip/hip_runtime.h>

// x (4096, 2, 1024) fp32.  P_i = x[i,0,:], A_j = x[i,1,:]
// out[0] = 1.0 exactly; out[1] = prec1 = 100*mean(argmax_j sim[i,j] == i)
// argmax_j sim[i,j] == argmax_j dot(P_i,A_j)*inv_norm(A_j).
// R17 = R16 resubmitted verbatim (R16 bench was an infra failure: container
// died twice before any profile; kernel audit found no hang/correctness
// defect -- uniform barriers, slack vmcnt(0), WAR-safe dbuf handoff).
// R16 theory: R15 was ~80% stalled (144 barriers/dispatch, 9/tile, ~68cyc
// MFMA between them; vmcnt(0) drained loads issued only 1 phase earlier).
// All 4 phases of a tile read ONLY cbuf and stage ONLY nbuf -> no intra-tile
// hazard -> 1 barrier/tile:
//   { vmcnt(0) ; s_barrier ; issue 8 stage loads (t+1 -> nbuf) ;
//     4 barrier-free phases of 6 ds_read + 8 MFMA from cbuf }
// vmcnt(0) waits loads issued a FULL tile earlier (slack-drained, T4).
// Memory layout, frag map, prep, epilogue identical to R15 (proven passing).
// Frag-order map (R4/R9/R11-verified): block fb region = 64KB at fb*65536;
// byte = kh*1024 + lane*16 -> (row = fb*32 + (lane&31), k = kh*16+(lane>>5)*8..+8).

#define NROWS 4096
#define DDIM  1024
#define XSTR  2048

typedef unsigned int u32;
typedef unsigned long long u64;
typedef __attribute__((ext_vector_type(8))) short bf16x8;
typedef __attribute__((ext_vector_type(8))) unsigned short u16x8;
typedef __attribute__((ext_vector_type(16))) float f32x16;

__device__ __forceinline__ unsigned int fkey(float f) {
    unsigned int u = __float_as_uint(f);
    return (u & 0x80000000u) ? ~u : (u | 0x80000000u);
}

__device__ __forceinline__ u64 shfl_xor_u64(u64 v, int m) {
    unsigned int lo = (unsigned int)v;
    unsigned int hi = (unsigned int)(v >> 32);
    lo = __shfl_xor(lo, m, 64);
    hi = __shfl_xor(hi, m, 64);
    return ((u64)hi << 32) | lo;
}

__device__ __forceinline__ unsigned short f2bf(float f) {
    unsigned u = __float_as_uint(f);
    return (unsigned short)((u + 0x7FFFu + ((u >> 16) & 1u)) >> 16);
}

// Workspace layout (bytes):
#define PF_OFF   0u
#define AF_OFF   8388608u
#define INV_OFF  16777216u
#define PCK_OFF  16793600u
#define DONE_OFF 16826368u
#define WS_NEED  16826432u

// ---- prep: norms (one wave per row, coalesced) + zero packed/done ----
__global__ __launch_bounds__(256) void norms2_kernel(const float* __restrict__ x,
                                                     float* __restrict__ inv_an,
                                                     u64* __restrict__ packed,
                                                     unsigned int* __restrict__ done) {
    int gid  = blockIdx.x * 256 + threadIdx.x;
    int j    = gid >> 6;
    int lane = threadIdx.x & 63;
    if (gid < NROWS) packed[gid] = 0ULL;
    if (gid == 0) *done = 0u;
    const float4* a = (const float4*)(x + (size_t)j * XSTR + DDIM);
    float s = 0.0f;
#pragma unroll
    for (int i = 0; i < 4; ++i) {
        float4 v = a[lane + i * 64];
        s += v.x * v.x + v.y * v.y + v.z * v.z + v.w * v.w;
    }
#pragma unroll
    for (int off = 32; off > 0; off >>= 1) s += __shfl_down(s, off, 64);
    if (lane == 0) inv_an[j] = 1.0f / sqrtf(s);
}

// ---- prep: fp32 -> bf16 fragment conversion, one thread per 16B chunk ----
// cid = fb*4096 + kh*64 + lane; coalesced 16B writes; full-occupancy MLP.
__global__ __launch_bounds__(256) void conv_kernel(const float* __restrict__ x,
                                                   unsigned short* __restrict__ Pf,
                                                   unsigned short* __restrict__ Af) {
    const int cid  = blockIdx.x * 256 + threadIdx.x;
    const int lane = cid & 63;
    const int kh   = (cid >> 6) & 63;
    const int fb   = cid >> 12;
    const int row  = fb * 32 + (lane & 31);
    const int col  = kh * 16 + (lane >> 5) * 8;

    const float* px = x + (size_t)row * XSTR + col;
    float4 p0 = *(const float4*)(px);
    float4 p1 = *(const float4*)(px + 4);
    float4 a0 = *(const float4*)(px + DDIM);
    float4 a1 = *(const float4*)(px + DDIM + 4);

    u16x8 pv, av;
    pv[0] = f2bf(p0.x); pv[1] = f2bf(p0.y); pv[2] = f2bf(p0.z); pv[3] = f2bf(p0.w);
    pv[4] = f2bf(p1.x); pv[5] = f2bf(p1.y); pv[6] = f2bf(p1.z); pv[7] = f2bf(p1.w);
    av[0] = f2bf(a0.x); av[1] = f2bf(a0.y); av[2] = f2bf(a0.z); av[3] = f2bf(a0.w);
    av[4] = f2bf(a1.x); av[5] = f2bf(a1.y); av[6] = f2bf(a1.z); av[7] = f2bf(a1.w);

    *(u16x8*)(Pf + (size_t)cid * 8) = pv;
    *(u16x8*)(Af + (size_t)cid * 8) = av;
}

// ---- MFMA GEMM + argmax + fused finalize, LDS-staged, 1 barrier/tile ----
// 256x256 block tile, 8 waves (4m x 2n) of 64x128. Grid 256, XCD-swizzled.
// LDS per buffer (64KB): [P: kh_l*8KB + fb_l*1KB] [A: +32KB, same]; x2 dbuf.
// Wave w stages frag-block fb_l=w for both P and A (8 gload_lds per tile).
__global__ __launch_bounds__(512, 2) void mfma_gemm_argmax(const unsigned short* __restrict__ Pf,
                                                           const unsigned short* __restrict__ Af,
                                                           const float* __restrict__ inv_an,
                                                           u64* __restrict__ packed,
                                                           unsigned int* __restrict__ done,
                                                           float* __restrict__ out) {
    __shared__ __align__(16) unsigned int lds[32768];  // 128 KB, 2 x 64KB buffers
    __shared__ unsigned int lastflag;
    __shared__ int cnt[8];

    const int bid = blockIdx.x;
    const int xcd = bid & 7;
    const int slt = bid >> 3;                       // 0..31
    const int rblk = (xcd >> 1) * 4 + (slt >> 3);   // 0..15
    const int cblk = (xcd & 1) * 8 + (slt & 7);     // 0..15
    const int r0 = rblk * 256;
    const int c0 = cblk * 256;

    const int wave = threadIdx.x >> 6;  // 0..7
    const int lane = threadIdx.x & 63;
    const int l31 = lane & 31;
    const int lh = lane >> 5;
    const int wm = wave & 3;   // m-quarter: rows wm*64..+63
    const int wn = wave >> 2;  // n-half:    cols wn*128..+127

    // per-wave global stage pointers: wave stages frag-block fb_l = wave
    const char* gPs = (const char*)Pf + (((size_t)(rblk * 8 + wave)) << 16) + (size_t)lane * 16;
    const char* gAs = (const char*)Af + (((size_t)(cblk * 8 + wave)) << 16) + (size_t)lane * 16;

    f32x16 zero16 = {0.f,0.f,0.f,0.f,0.f,0.f,0.f,0.f,0.f,0.f,0.f,0.f,0.f,0.f,0.f,0.f};
    f32x16 acc[2][4];
#pragma unroll
    for (int i = 0; i < 2; ++i)
#pragma unroll
        for (int j = 0; j < 4; ++j) acc[i][j] = zero16;

    // ---- prologue: stage tile 0 into buffer 0 (8 loads per wave) ----
#pragma unroll
    for (int kh_l = 0; kh_l < 4; ++kh_l) {
        __builtin_amdgcn_global_load_lds((const u32*)(gPs + ((size_t)kh_l << 10)),
                                         &lds[kh_l * 2048 + wave * 256], 16, 0, 0);
        __builtin_amdgcn_global_load_lds((const u32*)(gAs + ((size_t)kh_l << 10)),
                                         &lds[8192 + kh_l * 2048 + wave * 256], 16, 0, 0);
    }

    // ---- K loop: 16 tiles of BK=64, ONE barrier per tile ----
    for (int t = 0; t < 16; ++t) {
        const int cb = t & 1;
        const int cbuf = cb * 16384;
        const int nbuf = (cb ^ 1) * 16384;

        // my 8 loads for tile t were issued one full tile ago -> slack drain
        asm volatile("s_waitcnt vmcnt(0)" ::: "memory");
        __builtin_amdgcn_s_barrier();   // all loads landed; all done reading nbuf
        __builtin_amdgcn_sched_barrier(0);

        // issue all 8 stage loads for tile t+1 immediately (max slack)
        if (t + 1 < 16) {
#pragma unroll
            for (int kh_l = 0; kh_l < 4; ++kh_l) {
                const size_t go = ((size_t)((t + 1) * 4 + kh_l)) << 10;
                __builtin_amdgcn_global_load_lds((const u32*)(gPs + go),
                                                 &lds[nbuf + kh_l * 2048 + wave * 256], 16, 0, 0);
                __builtin_amdgcn_global_load_lds((const u32*)(gAs + go),
                                                 &lds[nbuf + 8192 + kh_l * 2048 + wave * 256], 16, 0, 0);
            }
        }

        // 4 barrier-free phases; compiler pipelines ds_read under MFMA
        __builtin_amdgcn_s_setprio(1);
#pragma unroll
        for (int kh_l = 0; kh_l < 4; ++kh_l) {
            const u32* bp = &lds[cbuf + kh_l * 2048 + (wm * 2) * 256 + lane * 4];
            bf16x8 f_p0 = *(const bf16x8*)(bp);
            bf16x8 f_p1 = *(const bf16x8*)(bp + 256);
            const u32* ba = &lds[cbuf + 8192 + kh_l * 2048 + (wn * 4) * 256 + lane * 4];
            bf16x8 f_a0 = *(const bf16x8*)(ba);
            bf16x8 f_a1 = *(const bf16x8*)(ba + 256);
            bf16x8 f_a2 = *(const bf16x8*)(ba + 512);
            bf16x8 f_a3 = *(const bf16x8*)(ba + 768);

            acc[0][0] = __builtin_amdgcn_mfma_f32_32x32x16_bf16(f_p0, f_a0, acc[0][0], 0, 0, 0);
            acc[0][1] = __builtin_amdgcn_mfma_f32_32x32x16_bf16(f_p0, f_a1, acc[0][1], 0, 0, 0);
            acc[0][2] = __builtin_amdgcn_mfma_f32_32x32x16_bf16(f_p0, f_a2, acc[0][2], 0, 0, 0);
            acc[0][3] = __builtin_amdgcn_mfma_f32_32x32x16_bf16(f_p0, f_a3, acc[0][3], 0, 0, 0);
            acc[1][0] = __builtin_amdgcn_mfma_f32_32x32x16_bf16(f_p1, f_a0, acc[1][0], 0, 0, 0);
            acc[1][1] = __builtin_amdgcn_mfma_f32_32x32x16_bf16(f_p1, f_a1, acc[1][1], 0, 0, 0);
            acc[1][2] = __builtin_amdgcn_mfma_f32_32x32x16_bf16(f_p1, f_a2, acc[1][2], 0, 0, 0);
            acc[1][3] = __builtin_amdgcn_mfma_f32_32x32x16_bf16(f_p1, f_a3, acc[1][3], 0, 0, 0);
        }
        __builtin_amdgcn_s_setprio(0);
    }

    // ---- epilogue: scale by inv_an, packed argmax ----
    float ian[4];
#pragma unroll
    for (int nt = 0; nt < 4; ++nt) ian[nt] = inv_an[c0 + wn * 128 + nt * 32 + l31];

    // 32x32 C/D layout (m74/m101): col = lane&31, row = (reg&3)+8*(reg>>2)+4*(lane>>5)
#pragma unroll
    for (int mt = 0; mt < 2; ++mt)
#pragma unroll
        for (int reg = 0; reg < 16; ++reg) {
            const int row = r0 + wm * 64 + mt * 32 + (reg & 3) + 8 * (reg >> 2) + 4 * lh;
            u64 best = 0ULL;
#pragma unroll
            for (int nt = 0; nt < 4; ++nt) {
                const int col = c0 + wn * 128 + nt * 32 + l31;
                const float v = acc[mt][nt][reg] * ian[nt];
                const u64 p = ((u64)fkey(v) << 32) | (unsigned int)(~col);
                best = best > p ? best : p;
            }
#pragma unroll
            for (int m = 1; m <= 16; m <<= 1) {
                const u64 o = shfl_xor_u64(best, m);
                best = best > o ? best : o;
            }
            if (l31 == 0) atomicMax(&packed[row], best);
        }

    // ---- fused finalize: last block counts and writes out ----
    __syncthreads();
    if (threadIdx.x == 0) {
        __threadfence();  // publish this block's atomicMax results
        unsigned int old = atomicAdd(done, 1u);
        lastflag = (old == 255u) ? 1u : 0u;
    }
    __syncthreads();
    if (lastflag) {
        int c = 0;
        for (int r = threadIdx.x; r < NROWS; r += 512) {
            u64 v = atomicAdd(&packed[r], 0ULL);  // device-coherent read
            unsigned int col = ~(unsigned int)(v & 0xFFFFFFFFULL);
            c += (col == (unsigned int)r) ? 1 : 0;
        }
#pragma unroll
        for (int off = 32; off > 0; off >>= 1) c += __shfl_down(c, off, 64);
        if ((threadIdx.x & 63) == 0) cnt[threadIdx.x >> 6] = c;
        __syncthreads();
        if (threadIdx.x == 0) {
            int tot = 0;
#pragma unroll
            for (int w = 0; w < 8; ++w) tot += cnt[w];
            out[0] = 1.0f;  // exp(temploss - stop_gradient(temploss)) == 1 exactly
            out[1] = 100.0f * (float)tot / (float)NROWS;
        }
    }
}

// ---------------- fallback fp32 path (proven R1) ----------------
__global__ __launch_bounds__(256) void norms_kernel(const float* __restrict__ x,
                                                    float* __restrict__ inv_an,
                                                    u64* __restrict__ packed) {
    int gid  = blockIdx.x * 256 + threadIdx.x;
    int j    = gid >> 6;
    int lane = threadIdx.x & 63;
    if (gid < NROWS) packed[gid] = 0ULL;
    const float4* a = (const float4*)(x + (size_t)j * XSTR + DDIM);
    float s = 0.0f;
#pragma unroll
    for (int i = 0; i < 4; ++i) {
        float4 v = a[lane + i * 64];
        s += v.x * v.x + v.y * v.y + v.z * v.z + v.w * v.w;
    }
#pragma unroll
    for (int off = 32; off > 0; off >>= 1) s += __shfl_down(s, off, 64);
    if (lane == 0) inv_an[j] = 1.0f / sqrtf(s);
}

__global__ __launch_bounds__(256) void gemm_argmax_kernel(const float* __restrict__ x,
                                                          const float* __restrict__ inv_an,
                                                          u64* __restrict__ packed) {
    __shared__ __align__(16) float Pt[16][128];
    __shared__ __align__(16) float At[16][128];
    const int r0 = blockIdx.x * 128;
    const int c0 = blockIdx.y * 128;
    const int t = threadIdx.x;
    const int tx = t & 15;
    const int ty = t >> 4;
    const int srow = t >> 1;
    const int skq = (t & 1) * 8;
    float acc[8][8];
#pragma unroll
    for (int r = 0; r < 8; ++r)
#pragma unroll
        for (int c = 0; c < 8; ++c) acc[r][c] = 0.0f;
    const float* gp = x + (size_t)(r0 + srow) * XSTR + skq;
    const float* ga = x + (size_t)(c0 + srow) * XSTR + DDIM + skq;
    for (int k0 = 0; k0 < DDIM; k0 += 16) {
        __syncthreads();
        float4 p0 = *(const float4*)(gp + k0);
        float4 p1 = *(const float4*)(gp + k0 + 4);
        float4 a0 = *(const float4*)(ga + k0);
        float4 a1 = *(const float4*)(ga + k0 + 4);
        Pt[skq + 0][srow] = p0.x; Pt[skq + 1][srow] = p0.y;
        Pt[skq + 2][srow] = p0.z; Pt[skq + 3][srow] = p0.w;
        Pt[skq + 4][srow] = p1.x; Pt[skq + 5][srow] = p1.y;
        Pt[skq + 6][srow] = p1.z; Pt[skq + 7][srow] = p1.w;
        At[skq + 0][srow] = a0.x; At[skq + 1][srow] = a0.y;
        At[skq + 2][srow] = a0.z; At[skq + 3][srow] = a0.w;
        At[skq + 4][srow] = a1.x; At[skq + 5][srow] = a1.y;
        At[skq + 6][srow] = a1.z; At[skq + 7][srow] = a1.w;
        __syncthreads();
#pragma unroll
        for (int kk = 0; kk < 16; ++kk) {
            float pr[8], ar[8];
            *(float4*)&pr[0] = *(const float4*)&Pt[kk][ty * 8];
            *(float4*)&pr[4] = *(const float4*)&Pt[kk][ty * 8 + 4];
            *(float4*)&ar[0] = *(const float4*)&At[kk][tx * 8];
            *(float4*)&ar[4] = *(const float4*)&At[kk][tx * 8 + 4];
#pragma unroll
            for (int r = 0; r < 8; ++r)
#pragma unroll
                for (int c = 0; c < 8; ++c) acc[r][c] += pr[r] * ar[c];
        }
    }
    float ian[8];
#pragma unroll
    for (int c = 0; c < 8; ++c) ian[c] = inv_an[c0 + tx * 8 + c];
#pragma unroll
    for (int r = 0; r < 8; ++r) {
        int row = r0 + ty * 8 + r;
        u64 best = 0ULL;
#pragma unroll
        for (int c = 0; c < 8; ++c) {
            int col = c0 + tx * 8 + c;
            float v = acc[r][c] * ian[c];
            u64 p = ((u64)fkey(v) << 32) | (unsigned int)(~col);
            best = best > p ? best : p;
        }
#pragma unroll
        for (int m = 1; m <= 8; m <<= 1) {
            u64 o = shfl_xor_u64(best, m);
            best = best > o ? best : o;
        }
        if (tx == 0) atomicMax(&packed[row], best);
    }
}

__global__ __launch_bounds__(256) void finalize_kernel(const u64* __restrict__ packed,
                                                       float* __restrict__ out) {
    __shared__ int cnt_s;
    int t = threadIdx.x;
    if (t == 0) cnt_s = 0;
    __syncthreads();
    int c = 0;
    for (int r = t; r < NROWS; r += 256) {
        unsigned int col = ~(unsigned int)(packed[r] & 0xFFFFFFFFULL);
        c += (col == (unsigned int)r) ? 1 : 0;
    }
#pragma unroll
    for (int off = 32; off > 0; off >>= 1) c += __shfl_down(c, off, 64);
    if ((t & 63) == 0) atomicAdd(&cnt_s, c);
    __syncthreads();
    if (t == 0) {
        out[0] = 1.0f;
        out[1] = 100.0f * (float)cnt_s / (float)NROWS;
    }
}

extern "C" void kernel_launch(void* const* d_in, const int* in_sizes, int n_in,
                              void* d_out, int out_size, void* d_ws, size_t ws_size,
                              hipStream_t stream) {
    (void)in_sizes; (void)n_in; (void)out_size;
    const float* x = (const float*)d_in[0];
    float* out = (float*)d_out;

    if (ws_size >= (size_t)WS_NEED) {
        char* ws = (char*)d_ws;
        unsigned short* Pf = (unsigned short*)(ws + PF_OFF);
        unsigned short* Af = (unsigned short*)(ws + AF_OFF);
        float* inv_an = (float*)(ws + INV_OFF);
        u64* packed = (u64*)(ws + PCK_OFF);
        unsigned int* done = (unsigned int*)(ws + DONE_OFF);

        norms2_kernel<<<NROWS / 4, 256, 0, stream>>>(x, inv_an, packed, done);
        conv_kernel<<<2048, 256, 0, stream>>>(x, Pf, Af);
        mfma_gemm_argmax<<<256, 512, 0, stream>>>(Pf, Af, inv_an, packed, done, out);
    } else {
        float* inv_an = (float*)d_ws;
        u64* packed = (u64*)((char*)d_ws + NROWS * sizeof(float));
        norms_kernel<<<NROWS / 4, 256, 0, stream>>>(x, inv_an, packed);
        dim3 grid(NROWS / 128, NROWS / 128);
        gemm_argmax_kernel<<<grid, 256, 0, stream>>>(x, inv_an, packed);
        finalize_kernel<<<1, 256, 0, stream>>>(packed, out);
    }
}